// Round 6
// baseline (573.573 us; speedup 1.0000x reference)
//
#include <hip/hip_runtime.h>
#include <hip/hip_bf16.h>

// Problem constants
#define B_   64
#define C_   3129
#define K_   10
#define DF_  768
#define F_   676      // 26*26
#define DW_  300
#define DWP_ 320      // DW_ padded to multiple of 64 (MFMA K-tile)
#define DT_  1024
#define NSEG 13       // o_bap f-segments: 676 = 13*52
#define FSEG 52
#define ASB  6        // attn_s m-blocks (ceil(676/128)) = pstats partials

typedef __attribute__((ext_vector_type(8))) short short8;   // 8 bf16
typedef __attribute__((ext_vector_type(4))) float floatx4;  // 4 fp32

// async 16B global -> LDS (wave-uniform LDS base + lane*16)
__device__ __forceinline__ void gload_lds16(const void* g, void* l) {
    __builtin_amdgcn_global_load_lds(
        (const __attribute__((address_space(1))) void*)g,
        (__attribute__((address_space(3))) void*)l, 16, 0, 0);
}

// ---------------------------------------------------------------------------
// 1. fused top-k (K=10, exact lax.top_k order) + class embedding per b.
__global__ void topk_emb_kernel(const float* __restrict__ logits,
                                const int* __restrict__ indices_table,
                                const float* __restrict__ word2vec,
                                int* __restrict__ topk_idx,
                                __hip_bfloat16* __restrict__ emb) {
    __shared__ float vals[C_];
    __shared__ float red_v[256];
    __shared__ int   red_i[256];
    __shared__ int   sel[K_];
    int b = blockIdx.x;
    int tid = threadIdx.x;
    for (int i = tid; i < C_; i += 256) vals[i] = logits[(size_t)b * C_ + i];
    __syncthreads();
    for (int s = 0; s < K_; ++s) {
        float bv = -INFINITY; int bi = 0x7fffffff;
        for (int i = tid; i < C_; i += 256) {
            float v = vals[i];
            if (v > bv) { bv = v; bi = i; }
        }
        red_v[tid] = bv; red_i[tid] = bi;
        __syncthreads();
        for (int st = 128; st > 0; st >>= 1) {
            if (tid < st) {
                float ov = red_v[tid + st]; int oi = red_i[tid + st];
                if (ov > red_v[tid] || (ov == red_v[tid] && oi < red_i[tid])) {
                    red_v[tid] = ov; red_i[tid] = oi;
                }
            }
            __syncthreads();
        }
        if (tid == 0) {
            sel[s] = red_i[0];
            topk_idx[b * K_ + s] = red_i[0];
            vals[red_i[0]] = -INFINITY;
        }
        __syncthreads();
    }
    for (int idx = tid; idx < K_ * DWP_; idx += 256) {
        int j  = idx % DWP_;
        int kk = idx / DWP_;
        float s = 0.f;
        if (j < DW_) {
            const int* tbl = indices_table + (size_t)sel[kk] * 4;
            #pragma unroll
            for (int i = 0; i < 4; ++i) s += word2vec[(size_t)tbl[i] * DW_ + j];
            s *= 0.25f;
        }
        emb[((size_t)b * K_ + kk) * DWP_ + j] = (__hip_bfloat16)s;
    }
}

// ---------------------------------------------------------------------------
// Transpose body: src[R][Cc] fp32 -> dst[Cc][Rp] bf16, zero-padded rows >= R.
__device__ __forceinline__ void tp_body(const float* __restrict__ s,
                                        __hip_bfloat16* __restrict__ d,
                                        int R, int Cc, int Rp, int c0, int r0) {
    __shared__ float tile[64][65];
    int t = threadIdx.x;
    int cl = (t & 15) * 4;
    int rl = t >> 4;
    #pragma unroll
    for (int i = 0; i < 4; ++i) {
        int r = rl + i * 16;
        float4 v = make_float4(0.f, 0.f, 0.f, 0.f);
        if (r0 + r < R && c0 + cl < Cc)
            v = *(const float4*)(s + (size_t)(r0 + r) * Cc + c0 + cl);
        tile[r][cl + 0] = v.x; tile[r][cl + 1] = v.y;
        tile[r][cl + 2] = v.z; tile[r][cl + 3] = v.w;
    }
    __syncthreads();
    int cw = t >> 2;
    int r4 = (t & 3) * 16;
    if (c0 + cw < Cc) {
        __align__(16) __hip_bfloat16 buf[16];
        #pragma unroll
        for (int j = 0; j < 16; ++j) buf[j] = (__hip_bfloat16)tile[r4 + j][cw];
        float4* dp = (float4*)(d + (size_t)(c0 + cw) * Rp + r0 + r4);
        dp[0] = *(float4*)&buf[0];
        dp[1] = *(float4*)&buf[8];
    }
}

// ftm transpose (z-batched) -- fallback path for chunked (small ws) mode
__global__ __launch_bounds__(256)
void transpose_ftm(const float* __restrict__ src, __hip_bfloat16* __restrict__ dst) {
    tp_body(src + (size_t)blockIdx.z * DF_ * F_,
            dst + (size_t)blockIdx.z * F_ * DF_,
            DF_, F_, DF_, blockIdx.x * 64, blockIdx.y * 64);
}

// weight transposes only -- fallback path
__global__ __launch_bounds__(256)
void transpose_weights(const float* __restrict__ Wemb, __hip_bfloat16* __restrict__ WembT,
                       const float* __restrict__ Wcls, __hip_bfloat16* __restrict__ WclsT,
                       const float* __restrict__ Wv,   __hip_bfloat16* __restrict__ WvT,
                       const float* __restrict__ Wbap, __hip_bfloat16* __restrict__ WbapT) {
    int id = blockIdx.x;
    const float* s; __hip_bfloat16* d; int R, Rp;
    if (id < 80)       { s = Wemb; d = WembT; R = DW_;  Rp = DWP_; }
    else if (id < 336) { s = Wcls; d = WclsT; R = DT_;  Rp = DT_;  id -= 80;  }
    else if (id < 528) { s = Wv;   d = WvT;   R = DF_;  Rp = DF_;  id -= 336; }
    else               { s = Wbap; d = WbapT; R = DT_;  Rp = DT_;  id -= 528; }
    int bx = id & 15;
    int by = id >> 4;
    tp_body(s, d, R, DT_, Rp, bx * 64, by * 64);
}

// all 4 weight transposes + full ftm transpose in ONE dispatch.
__global__ __launch_bounds__(256)
void transpose_all(const float* __restrict__ Wemb, __hip_bfloat16* __restrict__ WembT,
                   const float* __restrict__ Wcls, __hip_bfloat16* __restrict__ WclsT,
                   const float* __restrict__ Wv,   __hip_bfloat16* __restrict__ WvT,
                   const float* __restrict__ Wbap, __hip_bfloat16* __restrict__ WbapT,
                   const float* __restrict__ ftm,  __hip_bfloat16* __restrict__ ftm_t) {
    int id = blockIdx.x;
    if (id >= 784) {
        id -= 784;
        int z = id / 132;
        int t2 = id % 132;
        int bx = t2 % 11, by = t2 / 11;
        tp_body(ftm + (size_t)z * DF_ * F_, ftm_t + (size_t)z * F_ * DF_,
                DF_, F_, DF_, bx * 64, by * 64);
        return;
    }
    const float* s; __hip_bfloat16* d; int R, Rp;
    if (id < 80)       { s = Wemb; d = WembT; R = DW_;  Rp = DWP_; }
    else if (id < 336) { s = Wcls; d = WclsT; R = DT_;  Rp = DT_;  id -= 80;  }
    else if (id < 528) { s = Wv;   d = WvT;   R = DF_;  Rp = DF_;  id -= 336; }
    else               { s = Wbap; d = WbapT; R = DT_;  Rp = DT_;  id -= 528; }
    int bx = id & 15;
    int by = id >> 4;
    tp_body(s, d, R, DT_, Rp, bx * 64, by * 64);
}

// ---------------------------------------------------------------------------
// MFMA bf16 GEMM: C[M][N] = act(A[M][Kp] @ Bt[N][Kp]^T + bias)
// 128x128 tile, BK=64, global_load_lds w16 with XOR chunk swizzle, coalesced
// LDS epilogue (OUTBF=1), XCD-bijective remap.
template <int RELU, int OUTBF>
__global__ __launch_bounds__(256)
void gemm_mfma(const __hip_bfloat16* __restrict__ A,
               const __hip_bfloat16* __restrict__ Bt,
               const float* __restrict__ bias,
               void* __restrict__ Cout, int M, int N, int Kp) {
    __shared__ __align__(16) char smem[34816];       // max(As+Bs, C-tile 128x136)
    __hip_bfloat16* As = (__hip_bfloat16*)smem;      // [128][64]
    __hip_bfloat16* Bs = As + 128 * 64;              // [128][64]
    int tid = threadIdx.x;
    int wave = tid >> 6, lane = tid & 63;
    int quad = lane >> 4, l16 = lane & 15;
    int wm = (wave & 1) * 64, wn = (wave >> 1) * 64;

    // XCD-aware bijective remap (m204)
    int gx = gridDim.x;
    int nwg = gx * gridDim.y;
    int flat = blockIdx.y * gx + blockIdx.x;
    int q = nwg >> 3, r = nwg & 7;
    int xcd = flat & 7, lid = flat >> 3;
    int o = (xcd < r ? xcd * (q + 1) : r * (q + 1) + (xcd - r) * q) + lid;
    int n0 = (o % gx) * 128;
    int m0 = (o / gx) * 128;

    floatx4 acc[4][4];
    #pragma unroll
    for (int i = 0; i < 4; ++i)
        #pragma unroll
        for (int j = 0; j < 4; ++j)
            acc[i][j] = (floatx4){0.f, 0.f, 0.f, 0.f};

    int rsub = lane >> 3;
    int gchunk = (lane & 7) ^ rsub;

    int arow[4], brow[4];
    #pragma unroll
    for (int i = 0; i < 4; ++i) {
        arow[i] = wm + i * 16 + l16;
        brow[i] = wn + i * 16 + l16;
    }

    for (int k0 = 0; k0 < Kp; k0 += 64) {
        #pragma unroll
        for (int c = 0; c < 4; ++c) {
            int grp = wave * 4 + c;
            int row = grp * 8 + rsub;
            int ra = m0 + row; if (ra >= M) ra = M - 1;   // clamp: junk unused
            gload_lds16(A + (size_t)ra * Kp + k0 + gchunk * 8, As + grp * 512);
            gload_lds16(Bt + (size_t)(n0 + row) * Kp + k0 + gchunk * 8, Bs + grp * 512);
        }
        __syncthreads();
        #pragma unroll
        for (int ks = 0; ks < 2; ++ks) {
            short8 af[4], bf[4];
            #pragma unroll
            for (int mi = 0; mi < 4; ++mi)
                af[mi] = *(const short8*)&As[arow[mi] * 64 +
                            ((((ks << 2) | quad) ^ (arow[mi] & 7)) << 3)];
            #pragma unroll
            for (int ni = 0; ni < 4; ++ni)
                bf[ni] = *(const short8*)&Bs[brow[ni] * 64 +
                            ((((ks << 2) | quad) ^ (brow[ni] & 7)) << 3)];
            #pragma unroll
            for (int mi = 0; mi < 4; ++mi)
                #pragma unroll
                for (int ni = 0; ni < 4; ++ni)
                    acc[mi][ni] = __builtin_amdgcn_mfma_f32_16x16x32_bf16(
                        af[mi], bf[ni], acc[mi][ni], 0, 0, 0);
        }
        __syncthreads();
    }

    // C/D mapping: col = lane&15, row = quad*4 + reg  [measured m89/m91]
    float bn[4];
    #pragma unroll
    for (int ni = 0; ni < 4; ++ni) bn[ni] = bias[n0 + wn + ni * 16 + l16];

    if (OUTBF) {
        __hip_bfloat16* Cs = (__hip_bfloat16*)smem;
        #pragma unroll
        for (int mi = 0; mi < 4; ++mi)
            #pragma unroll
            for (int rr = 0; rr < 4; ++rr) {
                int row = wm + mi * 16 + quad * 4 + rr;
                #pragma unroll
                for (int ni = 0; ni < 4; ++ni) {
                    float val = acc[mi][ni][rr] + bn[ni];
                    if (RELU) val = fmaxf(val, 0.f);
                    Cs[row * 136 + wn + ni * 16 + l16] = (__hip_bfloat16)val;
                }
            }
        __syncthreads();
        #pragma unroll
        for (int j = 0; j < 8; ++j) {
            int ch = tid + 256 * j;              // 2048 chunks of 16 B
            int row = ch >> 4, c16 = ch & 15;
            int r = m0 + row;
            float4 val = *(const float4*)&Cs[row * 136 + c16 * 8];
            if (r < M)
                *(float4*)((__hip_bfloat16*)Cout + (size_t)r * N + n0 + c16 * 8) = val;
        }
    } else {
        #pragma unroll
        for (int mi = 0; mi < 4; ++mi)
            #pragma unroll
            for (int rr = 0; rr < 4; ++rr) {
                int r = m0 + wm + mi * 16 + quad * 4 + rr;
                if (r < M) {
                    #pragma unroll
                    for (int ni = 0; ni < 4; ++ni) {
                        float val = acc[mi][ni][rr] + bn[ni];
                        if (RELU) val = fmaxf(val, 0.f);
                        ((float*)Cout)[(size_t)r * N + n0 + wn + ni * 16 + l16] = val;
                    }
                }
            }
    }
}

// ---------------------------------------------------------------------------
// 4. attn scores via MFMA + fused per-block partial softmax stats.
//    s[bc,f,k] = sum_d v[bc,f,d] * cls[b0+bc,k,d]
//    pstats[bc][bx][k] = (m, l) over this block's valid f-rows (LSE-mergeable)
__global__ __launch_bounds__(256)
void attn_s_mfma(const __hip_bfloat16* __restrict__ v_buf,
                 const __hip_bfloat16* __restrict__ cls,
                 float* __restrict__ s_buf, float2* __restrict__ pstats,
                 int b0) {
    __shared__ __align__(16) __hip_bfloat16 As[128 * 64];  // 16 KB
    __shared__ __align__(16) __hip_bfloat16 Bs[16 * 64];   // 2 KB
    __shared__ float2 wred[4][16];
    int tid = threadIdx.x;
    int wave = tid >> 6, lane = tid & 63;
    int quad = lane >> 4, l16 = lane & 15;
    int bc = blockIdx.y;
    int b = b0 + bc;
    int f0 = blockIdx.x * 128;           // 6 m-tiles cover 768 >= 676
    int wm = wave * 32;                  // each wave: 2 m-frags (32 f rows)

    int rsub = lane >> 3;
    int gchunk = (lane & 7) ^ rsub;

    floatx4 acc[2];
    acc[0] = (floatx4){0.f, 0.f, 0.f, 0.f};
    acc[1] = (floatx4){0.f, 0.f, 0.f, 0.f};

    int arow[2];
    arow[0] = wm + l16;
    arow[1] = wm + 16 + l16;

    for (int k0 = 0; k0 < DT_; k0 += 64) {
        #pragma unroll
        for (int c = 0; c < 4; ++c) {
            int grp = wave * 4 + c;
            int row = grp * 8 + rsub;
            int fa = f0 + row; if (fa >= F_) fa = F_ - 1;   // clamp: junk unused
            gload_lds16(v_buf + ((size_t)bc * F_ + fa) * DT_ + k0 + gchunk * 8,
                        As + grp * 512);
        }
        if (wave == 0) {                 // wave-uniform branch
            #pragma unroll
            for (int c = 0; c < 2; ++c) {
                int row = c * 8 + rsub;  // 0..15
                int rc = row < K_ ? row : K_ - 1;
                gload_lds16(cls + ((size_t)b * K_ + rc) * DT_ + k0 + gchunk * 8,
                            Bs + c * 512);
            }
        }
        __syncthreads();
        #pragma unroll
        for (int ks = 0; ks < 2; ++ks) {
            short8 bf = *(const short8*)&Bs[l16 * 64 +
                            ((((ks << 2) | quad) ^ (l16 & 7)) << 3)];
            #pragma unroll
            for (int mi = 0; mi < 2; ++mi) {
                short8 af = *(const short8*)&As[arow[mi] * 64 +
                                ((((ks << 2) | quad) ^ (arow[mi] & 7)) << 3)];
                acc[mi] = __builtin_amdgcn_mfma_f32_16x16x32_bf16(
                    af, bf, acc[mi], 0, 0, 0);
            }
        }
        __syncthreads();
    }

    // C/D: col = l16 (class k), row = quad*4 + rr (f within frag)
    if (l16 < K_) {
        #pragma unroll
        for (int mi = 0; mi < 2; ++mi)
            #pragma unroll
            for (int rr = 0; rr < 4; ++rr) {
                int f = f0 + wm + mi * 16 + quad * 4 + rr;
                if (f < F_)
                    s_buf[((size_t)bc * F_ + f) * K_ + l16] = acc[mi][rr];
            }
    }

    // ---- partial softmax stats (per k = l16) over this block's valid rows
    float mp = -INFINITY, lp = 0.f;
    #pragma unroll
    for (int mi = 0; mi < 2; ++mi)
        #pragma unroll
        for (int rr = 0; rr < 4; ++rr) {
            int f = f0 + wm + mi * 16 + quad * 4 + rr;
            if (f < F_) mp = fmaxf(mp, acc[mi][rr]);
        }
    if (mp > -INFINITY) {
        #pragma unroll
        for (int mi = 0; mi < 2; ++mi)
            #pragma unroll
            for (int rr = 0; rr < 4; ++rr) {
                int f = f0 + wm + mi * 16 + quad * 4 + rr;
                if (f < F_) lp += __expf(acc[mi][rr] - mp);
            }
    }
    #pragma unroll
    for (int off = 16; off < 64; off <<= 1) {     // merge across quads
        float mo = __shfl_xor(mp, off);
        float lo = __shfl_xor(lp, off);
        float mn = fmaxf(mp, mo);
        float ln = (mp > -INFINITY ? lp * __expf(mp - mn) : 0.f)
                 + (mo > -INFINITY ? lo * __expf(mo - mn) : 0.f);
        mp = mn; lp = ln;
    }
    if (lane < 16) wred[wave][l16] = make_float2(mp, lp);
    __syncthreads();
    if (wave == 0 && lane < K_) {
        float m = -INFINITY, l = 0.f;
        #pragma unroll
        for (int w = 0; w < 4; ++w) {
            float2 p = wred[w][lane];
            float mn = fmaxf(m, p.x);
            l = (m > -INFINITY ? l * __expf(m - mn) : 0.f)
              + (p.x > -INFINITY ? p.y * __expf(p.x - mn) : 0.f);
            m = mn;
        }
        pstats[((size_t)bc * ASB + blockIdx.x) * K_ + lane] = make_float2(m, l);
    }
}

// ---------------------------------------------------------------------------
// 6. partial bap over f-segment; merges the ASB pstats partials in prologue.
//    pp[seg][b][d] = sum_k cls[b,k,d] * sum_{f in seg} w[f,k]*v[bc,f,d]
__global__ __launch_bounds__(256)
void o_bap_partial(const __hip_bfloat16* __restrict__ v_buf,
                   const float* __restrict__ s_buf,
                   const float2* __restrict__ pstats,
                   const __hip_bfloat16* __restrict__ cls,
                   float* __restrict__ pp, int b0) {
    int bc = blockIdx.x, seg = blockIdx.y;
    int b = b0 + bc;
    int t = threadIdx.x;
    int f0 = seg * FSEG;
    __shared__ float wbuf[FSEG * K_];          // 520 floats
    __shared__ float mk[K_], rlk[K_];
    __shared__ float red[128 * 8];             // half-1 partial outputs
    if (t < K_) {
        float m = -INFINITY, l = 0.f;
        #pragma unroll
        for (int j = 0; j < ASB; ++j) {
            float2 p = pstats[((size_t)bc * ASB + j) * K_ + t];
            float mn = fmaxf(m, p.x);
            l = (m > -INFINITY ? l * __expf(m - mn) : 0.f)
              + (p.x > -INFINITY ? p.y * __expf(p.x - mn) : 0.f);
            m = mn;
        }
        mk[t] = m; rlk[t] = 1.f / l;
    }
    __syncthreads();
    for (int j = t; j < FSEG * K_; j += 256) {
        int k = j % K_;
        float sv = s_buf[((size_t)bc * F_ + f0) * K_ + j];
        wbuf[j] = __expf(sv - mk[k]) * rlk[k];
    }
    __syncthreads();
    int th = t & 127, half = t >> 7;
    int d0 = th * 8;
    int fs = half * (FSEG / 2);                // 0 or 26
    float acc[K_][8] = {};
    const __hip_bfloat16* vp = v_buf + ((size_t)bc * F_ + f0 + fs) * DT_ + d0;
    for (int f = 0; f < FSEG / 2; ++f) {
        union { float4 f4; __hip_bfloat16 h[8]; } u;
        u.f4 = *(const float4*)(vp + (size_t)f * DT_);
        float vv[8];
        #pragma unroll
        for (int i = 0; i < 8; ++i) vv[i] = (float)u.h[i];
        const float* wk = &wbuf[(fs + f) * K_];
        #pragma unroll
        for (int k = 0; k < K_; ++k)
            #pragma unroll
            for (int i = 0; i < 8; ++i) acc[k][i] += wk[k] * vv[i];
    }
    float outv[8] = {};
    union { float4 f4; __hip_bfloat16 h[8]; } cu;
    #pragma unroll
    for (int k = 0; k < K_; ++k) {
        cu.f4 = *(const float4*)(cls + ((size_t)b * K_ + k) * DT_ + d0);
        #pragma unroll
        for (int i = 0; i < 8; ++i) outv[i] += acc[k][i] * (float)cu.h[i];
    }
    if (half == 1) {
        *(float4*)&red[th * 8]     = *(float4*)&outv[0];
        *(float4*)&red[th * 8 + 4] = *(float4*)&outv[4];
    }
    __syncthreads();
    if (half == 0) {
        #pragma unroll
        for (int i = 0; i < 8; ++i) outv[i] += red[th * 8 + i];
        float* pd = pp + ((size_t)seg * B_ + b) * DT_ + d0;
        *(float4*)pd       = *(float4*)&outv[0];
        *(float4*)(pd + 4) = *(float4*)&outv[4];
    }
}

// ---------------------------------------------------------------------------
// 7. fused tail: bap = bf16(sum_seg pp); y = relu(bap @ Wbap + b_bap);
//    lg = y @ Wfc + bfc; scatter-atomicAdd into out (zeroed).
//    One dispatch replaces bap_combine + gemm(bap) + final_kernel.
//    grid (8,1): 128-col tiles of the DT_ y-dimension; M=64 rows.
__global__ __launch_bounds__(256)
void gemm_bap_final(const float* __restrict__ pp,
                    const __hip_bfloat16* __restrict__ Bt,   // Wbap_t [DT][DT]
                    const float* __restrict__ b_bap,
                    const float* __restrict__ Wfc,           // [DT][K_]
                    const float* __restrict__ bfc,
                    const int* __restrict__ topk_idx,
                    float* __restrict__ out) {
    __shared__ __align__(16) __hip_bfloat16 As[128 * 64];    // rows 64..127 junk
    __shared__ __align__(16) __hip_bfloat16 Bs[128 * 64];
    __shared__ float Wfc_s[128 * K_];
    int tid = threadIdx.x;
    int wave = tid >> 6, lane = tid & 63;
    int quad = lane >> 4, l16 = lane & 15;
    int wm = (wave & 1) * 64, wn = (wave >> 1) * 64;
    int n0 = blockIdx.x * 128;

    for (int i = tid; i < 128 * K_; i += 256)
        Wfc_s[i] = Wfc[(size_t)(n0 + i / K_) * K_ + (i % K_)];

    floatx4 acc[4][4];
    #pragma unroll
    for (int i = 0; i < 4; ++i)
        #pragma unroll
        for (int j = 0; j < 4; ++j)
            acc[i][j] = (floatx4){0.f, 0.f, 0.f, 0.f};

    int rsub = lane >> 3;
    int gchunk = (lane & 7) ^ rsub;

    int arow[4], brow[4];
    #pragma unroll
    for (int i = 0; i < 4; ++i) {
        arow[i] = wm + i * 16 + l16;
        brow[i] = wn + i * 16 + l16;
    }

    for (int k0 = 0; k0 < DT_; k0 += 64) {
        // B: async global->LDS (128 rows of Wbap_t)
        #pragma unroll
        for (int c = 0; c < 4; ++c) {
            int grp = wave * 4 + c;
            int row = grp * 8 + rsub;
            gload_lds16(Bt + (size_t)(n0 + row) * DT_ + k0 + gchunk * 8,
                        Bs + grp * 512);
        }
        // A: reg-stage -- sum 13 pp segments fp32, convert bf16, XOR-slot write
        #pragma unroll
        for (int cc = 0; cc < 2; ++cc) {
            int cell = tid + cc * 256;          // 512 cells = 64 rows x 8 chunks
            int row = cell >> 3, chunk = cell & 7;
            int slot = chunk ^ (row & 7);
            const float* sp = pp + (size_t)row * DT_ + k0 + chunk * 8;
            float4 aa = make_float4(0.f, 0.f, 0.f, 0.f);
            float4 bb = make_float4(0.f, 0.f, 0.f, 0.f);
            for (int sg = 0; sg < NSEG; ++sg) {
                const float4* p4 = (const float4*)(sp + (size_t)sg * (B_ * DT_));
                float4 x = p4[0], y = p4[1];
                aa.x += x.x; aa.y += x.y; aa.z += x.z; aa.w += x.w;
                bb.x += y.x; bb.y += y.y; bb.z += y.z; bb.w += y.w;
            }
            union { short8 s8; __hip_bfloat16 h[8]; } u;
            u.h[0] = (__hip_bfloat16)aa.x; u.h[1] = (__hip_bfloat16)aa.y;
            u.h[2] = (__hip_bfloat16)aa.z; u.h[3] = (__hip_bfloat16)aa.w;
            u.h[4] = (__hip_bfloat16)bb.x; u.h[5] = (__hip_bfloat16)bb.y;
            u.h[6] = (__hip_bfloat16)bb.z; u.h[7] = (__hip_bfloat16)bb.w;
            *(short8*)&As[row * 64 + slot * 8] = u.s8;
        }
        __syncthreads();
        #pragma unroll
        for (int ks = 0; ks < 2; ++ks) {
            short8 af[4], bf[4];
            #pragma unroll
            for (int mi = 0; mi < 4; ++mi)
                af[mi] = *(const short8*)&As[arow[mi] * 64 +
                            ((((ks << 2) | quad) ^ (arow[mi] & 7)) << 3)];
            #pragma unroll
            for (int ni = 0; ni < 4; ++ni)
                bf[ni] = *(const short8*)&Bs[brow[ni] * 64 +
                            ((((ks << 2) | quad) ^ (brow[ni] & 7)) << 3)];
            #pragma unroll
            for (int mi = 0; mi < 4; ++mi)
                #pragma unroll
                for (int ni = 0; ni < 4; ++ni)
                    acc[mi][ni] = __builtin_amdgcn_mfma_f32_16x16x32_bf16(
                        af[mi], bf[ni], acc[mi][ni], 0, 0, 0);
        }
        __syncthreads();
    }

    // epilogue: only waves with wm==0 hold real rows (r < 64)
    if (wm == 0) {
        float bn[4];
        #pragma unroll
        for (int ni = 0; ni < 4; ++ni) bn[ni] = b_bap[n0 + wn + ni * 16 + l16];
        #pragma unroll
        for (int mi = 0; mi < 4; ++mi)
            #pragma unroll
            for (int rr = 0; rr < 4; ++rr) {
                int r = mi * 16 + quad * 4 + rr;        // batch row b
                float rowk[K_];
                #pragma unroll
                for (int k = 0; k < K_; ++k) rowk[k] = 0.f;
                #pragma unroll
                for (int ni = 0; ni < 4; ++ni) {
                    int nl = wn + ni * 16 + l16;
                    float val = fmaxf(acc[mi][ni][rr] + bn[ni], 0.f);
                    const float* wf = &Wfc_s[nl * K_];
                    #pragma unroll
                    for (int k = 0; k < K_; ++k) rowk[k] += val * wf[k];
                }
                #pragma unroll
                for (int off = 1; off < 16; off <<= 1)
                    #pragma unroll
                    for (int k = 0; k < K_; ++k)
                        rowk[k] += __shfl_xor(rowk[k], off);
                if (l16 == 0) {
                    #pragma unroll
                    for (int k = 0; k < K_; ++k) {
                        float add = rowk[k];
                        if (blockIdx.x == 0 && wave == 0) add += bfc[k];
                        atomicAdd(&out[(size_t)r * C_ + topk_idx[r * K_ + k]], add);
                    }
                }
            }
    }
}

// ---------------------------------------------------------------------------
extern "C" void kernel_launch(void* const* d_in, const int* in_sizes, int n_in,
                              void* d_out, int out_size, void* d_ws, size_t ws_size,
                              hipStream_t stream) {
    const float* ftm           = (const float*)d_in[0];
    const float* logits        = (const float*)d_in[1];
    const int*   indices_table = (const int*)d_in[3];
    const float* word2vec      = (const float*)d_in[4];
    const float* W_emb         = (const float*)d_in[5];
    const float* b_emb         = (const float*)d_in[6];
    const float* W_cls         = (const float*)d_in[7];
    const float* b_cls         = (const float*)d_in[8];
    const float* W_v           = (const float*)d_in[9];
    const float* b_v           = (const float*)d_in[10];
    const float* W_bap         = (const float*)d_in[11];
    const float* b_bap         = (const float*)d_in[12];
    const float* W_fc          = (const float*)d_in[13];
    const float* b_fc          = (const float*)d_in[14];
    float* out = (float*)d_out;

    char* ws = (char*)d_ws;
    size_t off = 0;
    auto alloc = [&](size_t bytes) -> void* {
        void* p = ws + off;
        off = (off + bytes + 255) & ~(size_t)255;
        return p;
    };
    int*            topk_idx = (int*)           alloc((size_t)B_ * K_ * 4);
    __hip_bfloat16* emb_bf   = (__hip_bfloat16*)alloc((size_t)B_ * K_ * DWP_ * 2);
    __hip_bfloat16* cls1     = (__hip_bfloat16*)alloc((size_t)B_ * K_ * DT_ * 2);
    __hip_bfloat16* cls2     = (__hip_bfloat16*)alloc((size_t)B_ * K_ * DT_ * 2);
    __hip_bfloat16* Wemb_t   = (__hip_bfloat16*)alloc((size_t)DT_ * DWP_ * 2);
    __hip_bfloat16* Wcls_t   = (__hip_bfloat16*)alloc((size_t)DT_ * DT_ * 2);
    __hip_bfloat16* Wv_t     = (__hip_bfloat16*)alloc((size_t)DT_ * DF_ * 2);
    __hip_bfloat16* Wbap_t   = (__hip_bfloat16*)alloc((size_t)DT_ * DT_ * 2);
    float*          s_buf    = (float*)         alloc((size_t)B_ * F_ * K_ * 4);
    float2*         pstats   = (float2*)        alloc((size_t)B_ * ASB * K_ * 8);
    float*          pp       = (float*)         alloc((size_t)NSEG * B_ * DT_ * 4);

    // dynamic batch-chunk: fit ftm_t + v for nb batches in remaining ws
    size_t per_b = (size_t)F_ * DF_ * 2 + (size_t)F_ * DT_ * 2;
    size_t avail = (ws_size > off + 8192) ? ws_size - off - 8192 : 0;
    int nb = (int)(avail / per_b);
    if (nb > B_) nb = B_;
    if (nb < 1) nb = 1;
    __hip_bfloat16* ftm_t = (__hip_bfloat16*)alloc((size_t)nb * F_ * DF_ * 2);
    __hip_bfloat16* v_buf = (__hip_bfloat16*)alloc((size_t)nb * F_ * DT_ * 2);

    hipMemsetAsync(d_out, 0, (size_t)out_size * sizeof(float), stream);

    topk_emb_kernel<<<B_, 256, 0, stream>>>(logits, indices_table, word2vec,
                                            topk_idx, emb_bf);

    if (nb == B_) {
        transpose_all<<<784 + 132 * B_, 256, 0, stream>>>(
            W_emb, Wemb_t, W_cls, Wcls_t, W_v, Wv_t, W_bap, Wbap_t, ftm, ftm_t);
    } else {
        transpose_weights<<<784, 256, 0, stream>>>(
            W_emb, Wemb_t, W_cls, Wcls_t, W_v, Wv_t, W_bap, Wbap_t);
    }

    // cls path (MFMA, n-fastest grid)
    gemm_mfma<1, 1><<<dim3(DT_ / 128, (B_ * K_ + 127) / 128), 256, 0, stream>>>(
        emb_bf, Wemb_t, b_emb, cls1, B_ * K_, DT_, DWP_);
    gemm_mfma<1, 1><<<dim3(DT_ / 128, (B_ * K_ + 127) / 128), 256, 0, stream>>>(
        cls1, Wcls_t, b_cls, cls2, B_ * K_, DT_, DT_);

    // main path, chunked only if ws is small (nb == 64 -> single pass)
    for (int b0 = 0; b0 < B_; b0 += nb) {
        int cb = min(nb, B_ - b0);
        if (nb != B_) {
            transpose_ftm<<<dim3((F_ + 63) / 64, DF_ / 64, cb), 256, 0, stream>>>(
                ftm + (size_t)b0 * DF_ * F_, ftm_t);
        }
        int M = cb * F_;
        gemm_mfma<1, 1><<<dim3(DT_ / 128, (M + 127) / 128), 256, 0, stream>>>(
            ftm_t, Wv_t, b_v, v_buf, M, DT_, DF_);
        float* s_c = s_buf + (size_t)b0 * F_ * K_;
        attn_s_mfma<<<dim3(ASB, cb), 256, 0, stream>>>(
            v_buf, cls2, s_c, pstats, b0);
        o_bap_partial<<<dim3(cb, NSEG), 256, 0, stream>>>(
            v_buf, s_c, pstats, cls2, pp, b0);
    }

    gemm_bap_final<<<dim3(DT_ / 128, 1), 256, 0, stream>>>(
        pp, Wbap_t, b_bap, W_fc, b_fc, topk_idx, out);
}

// Round 7
// 457.368 us; speedup vs baseline: 1.2541x; 1.2541x over previous
//
#include <hip/hip_runtime.h>
#include <hip/hip_bf16.h>

// Problem constants
#define B_   64
#define C_   3129
#define K_   10
#define DF_  768
#define F_   676      // 26*26
#define DW_  300
#define DWP_ 320      // DW_ padded to multiple of 64 (MFMA K-tile)
#define DT_  1024
#define NSEG 13       // o_bap f-segments: 676 = 13*52
#define FSEG 52
#define ASB  6        // attn_s m-blocks (ceil(676/128)) = pstats partials

typedef __attribute__((ext_vector_type(8))) short short8;   // 8 bf16
typedef __attribute__((ext_vector_type(4))) float floatx4;  // 4 fp32

// async 16B global -> LDS (wave-uniform LDS base + lane*16)
__device__ __forceinline__ void gload_lds16(const void* g, void* l) {
    __builtin_amdgcn_global_load_lds(
        (const __attribute__((address_space(1))) void*)g,
        (__attribute__((address_space(3))) void*)l, 16, 0, 0);
}

// ---------------------------------------------------------------------------
// 1. fused top-k (K=10, exact lax.top_k order) + class embedding per b.
__global__ void topk_emb_kernel(const float* __restrict__ logits,
                                const int* __restrict__ indices_table,
                                const float* __restrict__ word2vec,
                                int* __restrict__ topk_idx,
                                __hip_bfloat16* __restrict__ emb) {
    __shared__ float vals[C_];
    __shared__ float red_v[256];
    __shared__ int   red_i[256];
    __shared__ int   sel[K_];
    int b = blockIdx.x;
    int tid = threadIdx.x;
    for (int i = tid; i < C_; i += 256) vals[i] = logits[(size_t)b * C_ + i];
    __syncthreads();
    for (int s = 0; s < K_; ++s) {
        float bv = -INFINITY; int bi = 0x7fffffff;
        for (int i = tid; i < C_; i += 256) {
            float v = vals[i];
            if (v > bv) { bv = v; bi = i; }
        }
        red_v[tid] = bv; red_i[tid] = bi;
        __syncthreads();
        for (int st = 128; st > 0; st >>= 1) {
            if (tid < st) {
                float ov = red_v[tid + st]; int oi = red_i[tid + st];
                if (ov > red_v[tid] || (ov == red_v[tid] && oi < red_i[tid])) {
                    red_v[tid] = ov; red_i[tid] = oi;
                }
            }
            __syncthreads();
        }
        if (tid == 0) {
            sel[s] = red_i[0];
            topk_idx[b * K_ + s] = red_i[0];
            vals[red_i[0]] = -INFINITY;
        }
        __syncthreads();
    }
    for (int idx = tid; idx < K_ * DWP_; idx += 256) {
        int j  = idx % DWP_;
        int kk = idx / DWP_;
        float s = 0.f;
        if (j < DW_) {
            const int* tbl = indices_table + (size_t)sel[kk] * 4;
            #pragma unroll
            for (int i = 0; i < 4; ++i) s += word2vec[(size_t)tbl[i] * DW_ + j];
            s *= 0.25f;
        }
        emb[((size_t)b * K_ + kk) * DWP_ + j] = (__hip_bfloat16)s;
    }
}

// ---------------------------------------------------------------------------
// Transpose body: src[R][Cc] fp32 -> dst[Cc][Rp] bf16, zero-padded rows >= R.
__device__ __forceinline__ void tp_body(const float* __restrict__ s,
                                        __hip_bfloat16* __restrict__ d,
                                        int R, int Cc, int Rp, int c0, int r0) {
    __shared__ float tile[64][65];
    int t = threadIdx.x;
    int cl = (t & 15) * 4;
    int rl = t >> 4;
    #pragma unroll
    for (int i = 0; i < 4; ++i) {
        int r = rl + i * 16;
        float4 v = make_float4(0.f, 0.f, 0.f, 0.f);
        if (r0 + r < R && c0 + cl < Cc)
            v = *(const float4*)(s + (size_t)(r0 + r) * Cc + c0 + cl);
        tile[r][cl + 0] = v.x; tile[r][cl + 1] = v.y;
        tile[r][cl + 2] = v.z; tile[r][cl + 3] = v.w;
    }
    __syncthreads();
    int cw = t >> 2;
    int r4 = (t & 3) * 16;
    if (c0 + cw < Cc) {
        __align__(16) __hip_bfloat16 buf[16];
        #pragma unroll
        for (int j = 0; j < 16; ++j) buf[j] = (__hip_bfloat16)tile[r4 + j][cw];
        float4* dp = (float4*)(d + (size_t)(c0 + cw) * Rp + r0 + r4);
        dp[0] = *(float4*)&buf[0];
        dp[1] = *(float4*)&buf[8];
    }
}

// ftm transpose (z-batched) -- fallback path for chunked (small ws) mode
__global__ __launch_bounds__(256)
void transpose_ftm(const float* __restrict__ src, __hip_bfloat16* __restrict__ dst) {
    tp_body(src + (size_t)blockIdx.z * DF_ * F_,
            dst + (size_t)blockIdx.z * F_ * DF_,
            DF_, F_, DF_, blockIdx.x * 64, blockIdx.y * 64);
}

// weight transposes only -- fallback path
__global__ __launch_bounds__(256)
void transpose_weights(const float* __restrict__ Wemb, __hip_bfloat16* __restrict__ WembT,
                       const float* __restrict__ Wcls, __hip_bfloat16* __restrict__ WclsT,
                       const float* __restrict__ Wv,   __hip_bfloat16* __restrict__ WvT,
                       const float* __restrict__ Wbap, __hip_bfloat16* __restrict__ WbapT) {
    int id = blockIdx.x;
    const float* s; __hip_bfloat16* d; int R, Rp;
    if (id < 80)       { s = Wemb; d = WembT; R = DW_;  Rp = DWP_; }
    else if (id < 336) { s = Wcls; d = WclsT; R = DT_;  Rp = DT_;  id -= 80;  }
    else if (id < 528) { s = Wv;   d = WvT;   R = DF_;  Rp = DF_;  id -= 336; }
    else               { s = Wbap; d = WbapT; R = DT_;  Rp = DT_;  id -= 528; }
    int bx = id & 15;
    int by = id >> 4;
    tp_body(s, d, R, DT_, Rp, bx * 64, by * 64);
}

// all 4 weight transposes + full ftm transpose in ONE dispatch.
__global__ __launch_bounds__(256)
void transpose_all(const float* __restrict__ Wemb, __hip_bfloat16* __restrict__ WembT,
                   const float* __restrict__ Wcls, __hip_bfloat16* __restrict__ WclsT,
                   const float* __restrict__ Wv,   __hip_bfloat16* __restrict__ WvT,
                   const float* __restrict__ Wbap, __hip_bfloat16* __restrict__ WbapT,
                   const float* __restrict__ ftm,  __hip_bfloat16* __restrict__ ftm_t) {
    int id = blockIdx.x;
    if (id >= 784) {
        id -= 784;
        int z = id / 132;
        int t2 = id % 132;
        int bx = t2 % 11, by = t2 / 11;
        tp_body(ftm + (size_t)z * DF_ * F_, ftm_t + (size_t)z * F_ * DF_,
                DF_, F_, DF_, bx * 64, by * 64);
        return;
    }
    const float* s; __hip_bfloat16* d; int R, Rp;
    if (id < 80)       { s = Wemb; d = WembT; R = DW_;  Rp = DWP_; }
    else if (id < 336) { s = Wcls; d = WclsT; R = DT_;  Rp = DT_;  id -= 80;  }
    else if (id < 528) { s = Wv;   d = WvT;   R = DF_;  Rp = DF_;  id -= 336; }
    else               { s = Wbap; d = WbapT; R = DT_;  Rp = DT_;  id -= 528; }
    int bx = id & 15;
    int by = id >> 4;
    tp_body(s, d, R, DT_, Rp, bx * 64, by * 64);
}

// ---------------------------------------------------------------------------
// MFMA bf16 GEMM: C[M][N] = act(A[M][Kp] @ Bt[N][Kp]^T + bias)
// 128x128 tile, BK=64, global_load_lds w16 with XOR chunk swizzle, coalesced
// LDS epilogue (OUTBF=1), XCD-bijective remap.
template <int RELU, int OUTBF>
__global__ __launch_bounds__(256)
void gemm_mfma(const __hip_bfloat16* __restrict__ A,
               const __hip_bfloat16* __restrict__ Bt,
               const float* __restrict__ bias,
               void* __restrict__ Cout, int M, int N, int Kp) {
    __shared__ __align__(16) char smem[34816];       // max(As+Bs, C-tile 128x136)
    __hip_bfloat16* As = (__hip_bfloat16*)smem;      // [128][64]
    __hip_bfloat16* Bs = As + 128 * 64;              // [128][64]
    int tid = threadIdx.x;
    int wave = tid >> 6, lane = tid & 63;
    int quad = lane >> 4, l16 = lane & 15;
    int wm = (wave & 1) * 64, wn = (wave >> 1) * 64;

    // XCD-aware bijective remap (m204)
    int gx = gridDim.x;
    int nwg = gx * gridDim.y;
    int flat = blockIdx.y * gx + blockIdx.x;
    int q = nwg >> 3, r = nwg & 7;
    int xcd = flat & 7, lid = flat >> 3;
    int o = (xcd < r ? xcd * (q + 1) : r * (q + 1) + (xcd - r) * q) + lid;
    int n0 = (o % gx) * 128;
    int m0 = (o / gx) * 128;

    floatx4 acc[4][4];
    #pragma unroll
    for (int i = 0; i < 4; ++i)
        #pragma unroll
        for (int j = 0; j < 4; ++j)
            acc[i][j] = (floatx4){0.f, 0.f, 0.f, 0.f};

    int rsub = lane >> 3;
    int gchunk = (lane & 7) ^ rsub;

    int arow[4], brow[4];
    #pragma unroll
    for (int i = 0; i < 4; ++i) {
        arow[i] = wm + i * 16 + l16;
        brow[i] = wn + i * 16 + l16;
    }

    for (int k0 = 0; k0 < Kp; k0 += 64) {
        #pragma unroll
        for (int c = 0; c < 4; ++c) {
            int grp = wave * 4 + c;
            int row = grp * 8 + rsub;
            int ra = m0 + row; if (ra >= M) ra = M - 1;   // clamp: junk unused
            gload_lds16(A + (size_t)ra * Kp + k0 + gchunk * 8, As + grp * 512);
            gload_lds16(Bt + (size_t)(n0 + row) * Kp + k0 + gchunk * 8, Bs + grp * 512);
        }
        __syncthreads();
        #pragma unroll
        for (int ks = 0; ks < 2; ++ks) {
            short8 af[4], bf[4];
            #pragma unroll
            for (int mi = 0; mi < 4; ++mi)
                af[mi] = *(const short8*)&As[arow[mi] * 64 +
                            ((((ks << 2) | quad) ^ (arow[mi] & 7)) << 3)];
            #pragma unroll
            for (int ni = 0; ni < 4; ++ni)
                bf[ni] = *(const short8*)&Bs[brow[ni] * 64 +
                            ((((ks << 2) | quad) ^ (brow[ni] & 7)) << 3)];
            #pragma unroll
            for (int mi = 0; mi < 4; ++mi)
                #pragma unroll
                for (int ni = 0; ni < 4; ++ni)
                    acc[mi][ni] = __builtin_amdgcn_mfma_f32_16x16x32_bf16(
                        af[mi], bf[ni], acc[mi][ni], 0, 0, 0);
        }
        __syncthreads();
    }

    // C/D mapping: col = lane&15, row = quad*4 + reg  [measured m89/m91]
    float bn[4];
    #pragma unroll
    for (int ni = 0; ni < 4; ++ni) bn[ni] = bias[n0 + wn + ni * 16 + l16];

    if (OUTBF) {
        __hip_bfloat16* Cs = (__hip_bfloat16*)smem;
        #pragma unroll
        for (int mi = 0; mi < 4; ++mi)
            #pragma unroll
            for (int rr = 0; rr < 4; ++rr) {
                int row = wm + mi * 16 + quad * 4 + rr;
                #pragma unroll
                for (int ni = 0; ni < 4; ++ni) {
                    float val = acc[mi][ni][rr] + bn[ni];
                    if (RELU) val = fmaxf(val, 0.f);
                    Cs[row * 136 + wn + ni * 16 + l16] = (__hip_bfloat16)val;
                }
            }
        __syncthreads();
        #pragma unroll
        for (int j = 0; j < 8; ++j) {
            int ch = tid + 256 * j;              // 2048 chunks of 16 B
            int row = ch >> 4, c16 = ch & 15;
            int r = m0 + row;
            float4 val = *(const float4*)&Cs[row * 136 + c16 * 8];
            if (r < M)
                *(float4*)((__hip_bfloat16*)Cout + (size_t)r * N + n0 + c16 * 8) = val;
        }
    } else {
        #pragma unroll
        for (int mi = 0; mi < 4; ++mi)
            #pragma unroll
            for (int rr = 0; rr < 4; ++rr) {
                int r = m0 + wm + mi * 16 + quad * 4 + rr;
                if (r < M) {
                    #pragma unroll
                    for (int ni = 0; ni < 4; ++ni) {
                        float val = acc[mi][ni][rr] + bn[ni];
                        if (RELU) val = fmaxf(val, 0.f);
                        ((float*)Cout)[(size_t)r * N + n0 + wn + ni * 16 + l16] = val;
                    }
                }
            }
    }
}

// ---------------------------------------------------------------------------
// 4. attn scores via MFMA + fused per-block partial softmax stats.
//    s[bc,f,k] = sum_d v[bc,f,d] * cls[b0+bc,k,d]
//    pstats[bc][bx][k] = (m, l) over this block's valid f-rows (LSE-mergeable)
__global__ __launch_bounds__(256)
void attn_s_mfma(const __hip_bfloat16* __restrict__ v_buf,
                 const __hip_bfloat16* __restrict__ cls,
                 float* __restrict__ s_buf, float2* __restrict__ pstats,
                 int b0) {
    __shared__ __align__(16) __hip_bfloat16 As[128 * 64];  // 16 KB
    __shared__ __align__(16) __hip_bfloat16 Bs[16 * 64];   // 2 KB
    __shared__ float2 wred[4][16];
    int tid = threadIdx.x;
    int wave = tid >> 6, lane = tid & 63;
    int quad = lane >> 4, l16 = lane & 15;
    int bc = blockIdx.y;
    int b = b0 + bc;
    int f0 = blockIdx.x * 128;           // 6 m-tiles cover 768 >= 676
    int wm = wave * 32;                  // each wave: 2 m-frags (32 f rows)

    int rsub = lane >> 3;
    int gchunk = (lane & 7) ^ rsub;

    floatx4 acc[2];
    acc[0] = (floatx4){0.f, 0.f, 0.f, 0.f};
    acc[1] = (floatx4){0.f, 0.f, 0.f, 0.f};

    int arow[2];
    arow[0] = wm + l16;
    arow[1] = wm + 16 + l16;

    for (int k0 = 0; k0 < DT_; k0 += 64) {
        #pragma unroll
        for (int c = 0; c < 4; ++c) {
            int grp = wave * 4 + c;
            int row = grp * 8 + rsub;
            int fa = f0 + row; if (fa >= F_) fa = F_ - 1;   // clamp: junk unused
            gload_lds16(v_buf + ((size_t)bc * F_ + fa) * DT_ + k0 + gchunk * 8,
                        As + grp * 512);
        }
        if (wave == 0) {                 // wave-uniform branch
            #pragma unroll
            for (int c = 0; c < 2; ++c) {
                int row = c * 8 + rsub;  // 0..15
                int rc = row < K_ ? row : K_ - 1;
                gload_lds16(cls + ((size_t)b * K_ + rc) * DT_ + k0 + gchunk * 8,
                            Bs + c * 512);
            }
        }
        __syncthreads();
        #pragma unroll
        for (int ks = 0; ks < 2; ++ks) {
            short8 bf = *(const short8*)&Bs[l16 * 64 +
                            ((((ks << 2) | quad) ^ (l16 & 7)) << 3)];
            #pragma unroll
            for (int mi = 0; mi < 2; ++mi) {
                short8 af = *(const short8*)&As[arow[mi] * 64 +
                                ((((ks << 2) | quad) ^ (arow[mi] & 7)) << 3)];
                acc[mi] = __builtin_amdgcn_mfma_f32_16x16x32_bf16(
                    af, bf, acc[mi], 0, 0, 0);
            }
        }
        __syncthreads();
    }

    // C/D: col = l16 (class k), row = quad*4 + rr (f within frag)
    if (l16 < K_) {
        #pragma unroll
        for (int mi = 0; mi < 2; ++mi)
            #pragma unroll
            for (int rr = 0; rr < 4; ++rr) {
                int f = f0 + wm + mi * 16 + quad * 4 + rr;
                if (f < F_)
                    s_buf[((size_t)bc * F_ + f) * K_ + l16] = acc[mi][rr];
            }
    }

    // ---- partial softmax stats (per k = l16) over this block's valid rows
    float mp = -INFINITY, lp = 0.f;
    #pragma unroll
    for (int mi = 0; mi < 2; ++mi)
        #pragma unroll
        for (int rr = 0; rr < 4; ++rr) {
            int f = f0 + wm + mi * 16 + quad * 4 + rr;
            if (f < F_) mp = fmaxf(mp, acc[mi][rr]);
        }
    if (mp > -INFINITY) {
        #pragma unroll
        for (int mi = 0; mi < 2; ++mi)
            #pragma unroll
            for (int rr = 0; rr < 4; ++rr) {
                int f = f0 + wm + mi * 16 + quad * 4 + rr;
                if (f < F_) lp += __expf(acc[mi][rr] - mp);
            }
    }
    #pragma unroll
    for (int off = 16; off < 64; off <<= 1) {     // merge across quads
        float mo = __shfl_xor(mp, off);
        float lo = __shfl_xor(lp, off);
        float mn = fmaxf(mp, mo);
        float ln = (mp > -INFINITY ? lp * __expf(mp - mn) : 0.f)
                 + (mo > -INFINITY ? lo * __expf(mo - mn) : 0.f);
        mp = mn; lp = ln;
    }
    if (lane < 16) wred[wave][l16] = make_float2(mp, lp);
    __syncthreads();
    if (wave == 0 && lane < K_) {
        float m = -INFINITY, l = 0.f;
        #pragma unroll
        for (int w = 0; w < 4; ++w) {
            float2 p = wred[w][lane];
            float mn = fmaxf(m, p.x);
            l = (m > -INFINITY ? l * __expf(m - mn) : 0.f)
              + (p.x > -INFINITY ? p.y * __expf(p.x - mn) : 0.f);
            m = mn;
        }
        pstats[((size_t)bc * ASB + blockIdx.x) * K_ + lane] = make_float2(m, l);
    }
}

// ---------------------------------------------------------------------------
// 6. partial bap over f-segment; merges the ASB pstats partials in prologue.
//    pp[seg][b][d] = sum_k cls[b,k,d] * sum_{f in seg} w[f,k]*v[bc,f,d]
__global__ __launch_bounds__(256)
void o_bap_partial(const __hip_bfloat16* __restrict__ v_buf,
                   const float* __restrict__ s_buf,
                   const float2* __restrict__ pstats,
                   const __hip_bfloat16* __restrict__ cls,
                   float* __restrict__ pp, int b0) {
    int bc = blockIdx.x, seg = blockIdx.y;
    int b = b0 + bc;
    int t = threadIdx.x;
    int f0 = seg * FSEG;
    __shared__ float wbuf[FSEG * K_];          // 520 floats
    __shared__ float mk[K_], rlk[K_];
    __shared__ float red[128 * 8];             // half-1 partial outputs
    if (t < K_) {
        float m = -INFINITY, l = 0.f;
        #pragma unroll
        for (int j = 0; j < ASB; ++j) {
            float2 p = pstats[((size_t)bc * ASB + j) * K_ + t];
            float mn = fmaxf(m, p.x);
            l = (m > -INFINITY ? l * __expf(m - mn) : 0.f)
              + (p.x > -INFINITY ? p.y * __expf(p.x - mn) : 0.f);
            m = mn;
        }
        mk[t] = m; rlk[t] = 1.f / l;
    }
    __syncthreads();
    for (int j = t; j < FSEG * K_; j += 256) {
        int k = j % K_;
        float sv = s_buf[((size_t)bc * F_ + f0) * K_ + j];
        wbuf[j] = __expf(sv - mk[k]) * rlk[k];
    }
    __syncthreads();
    int th = t & 127, half = t >> 7;
    int d0 = th * 8;
    int fs = half * (FSEG / 2);                // 0 or 26
    float acc[K_][8] = {};
    const __hip_bfloat16* vp = v_buf + ((size_t)bc * F_ + f0 + fs) * DT_ + d0;
    for (int f = 0; f < FSEG / 2; ++f) {
        union { float4 f4; __hip_bfloat16 h[8]; } u;
        u.f4 = *(const float4*)(vp + (size_t)f * DT_);
        float vv[8];
        #pragma unroll
        for (int i = 0; i < 8; ++i) vv[i] = (float)u.h[i];
        const float* wk = &wbuf[(fs + f) * K_];
        #pragma unroll
        for (int k = 0; k < K_; ++k)
            #pragma unroll
            for (int i = 0; i < 8; ++i) acc[k][i] += wk[k] * vv[i];
    }
    float outv[8] = {};
    union { float4 f4; __hip_bfloat16 h[8]; } cu;
    #pragma unroll
    for (int k = 0; k < K_; ++k) {
        cu.f4 = *(const float4*)(cls + ((size_t)b * K_ + k) * DT_ + d0);
        #pragma unroll
        for (int i = 0; i < 8; ++i) outv[i] += acc[k][i] * (float)cu.h[i];
    }
    if (half == 1) {
        *(float4*)&red[th * 8]     = *(float4*)&outv[0];
        *(float4*)&red[th * 8 + 4] = *(float4*)&outv[4];
    }
    __syncthreads();
    if (half == 0) {
        #pragma unroll
        for (int i = 0; i < 8; ++i) outv[i] += red[th * 8 + i];
        float* pd = pp + ((size_t)seg * B_ + b) * DT_ + d0;
        *(float4*)pd       = *(float4*)&outv[0];
        *(float4*)(pd + 4) = *(float4*)&outv[4];
    }
}

// 6b. combine segments -> bf16 bap  (256 blocks: fully parallel reduction;
// NEVER fuse this into the 8-block tail GEMM -- R6 post-mortem: that moves
// the pp reduction into a latency-bound serial regime, 186 us)
__global__ void bap_combine(const float* __restrict__ pp,
                            __hip_bfloat16* __restrict__ bap) {
    int idx = blockIdx.x * 256 + threadIdx.x;   // B_*DT_ total
    float s = 0.f;
    #pragma unroll
    for (int g = 0; g < NSEG; ++g) s += pp[idx + (size_t)g * B_ * DT_];
    bap[idx] = (__hip_bfloat16)s;
}

// ---------------------------------------------------------------------------
// 7. lg[b,k] = y[b,:] @ W_fc[:,k] + b_fc[k]; scatter into out
__global__ void final_kernel(const float* __restrict__ y,
                             const float* __restrict__ Wfc,
                             const float* __restrict__ bfc,
                             const int* __restrict__ topk_idx,
                             float* __restrict__ out) {
    int b = blockIdx.x, tid = threadIdx.x;
    int lane = tid & 63, wave = tid >> 6;
    float pk[K_] = {};
    for (int d = tid; d < DT_; d += 256) {
        float yv = y[(size_t)b * DT_ + d];
        #pragma unroll
        for (int k = 0; k < K_; ++k) pk[k] += yv * Wfc[(size_t)d * K_ + k];
    }
    __shared__ float wsum[4][K_];
    #pragma unroll
    for (int k = 0; k < K_; ++k) {
        float a = pk[k];
        #pragma unroll
        for (int off = 32; off > 0; off >>= 1) a += __shfl_down(a, off);
        if (lane == 0) wsum[wave][k] = a;
    }
    __syncthreads();
    if (tid < K_) {
        float lg = wsum[0][tid] + wsum[1][tid] + wsum[2][tid] + wsum[3][tid] + bfc[tid];
        out[(size_t)b * C_ + topk_idx[b * K_ + tid]] = lg;
    }
}

// ---------------------------------------------------------------------------
extern "C" void kernel_launch(void* const* d_in, const int* in_sizes, int n_in,
                              void* d_out, int out_size, void* d_ws, size_t ws_size,
                              hipStream_t stream) {
    const float* ftm           = (const float*)d_in[0];
    const float* logits        = (const float*)d_in[1];
    const int*   indices_table = (const int*)d_in[3];
    const float* word2vec      = (const float*)d_in[4];
    const float* W_emb         = (const float*)d_in[5];
    const float* b_emb         = (const float*)d_in[6];
    const float* W_cls         = (const float*)d_in[7];
    const float* b_cls         = (const float*)d_in[8];
    const float* W_v           = (const float*)d_in[9];
    const float* b_v           = (const float*)d_in[10];
    const float* W_bap         = (const float*)d_in[11];
    const float* b_bap         = (const float*)d_in[12];
    const float* W_fc          = (const float*)d_in[13];
    const float* b_fc          = (const float*)d_in[14];
    float* out = (float*)d_out;

    char* ws = (char*)d_ws;
    size_t off = 0;
    auto alloc = [&](size_t bytes) -> void* {
        void* p = ws + off;
        off = (off + bytes + 255) & ~(size_t)255;
        return p;
    };
    int*            topk_idx = (int*)           alloc((size_t)B_ * K_ * 4);
    __hip_bfloat16* emb_bf   = (__hip_bfloat16*)alloc((size_t)B_ * K_ * DWP_ * 2);
    __hip_bfloat16* cls1     = (__hip_bfloat16*)alloc((size_t)B_ * K_ * DT_ * 2);
    __hip_bfloat16* cls2     = (__hip_bfloat16*)alloc((size_t)B_ * K_ * DT_ * 2);
    __hip_bfloat16* Wemb_t   = (__hip_bfloat16*)alloc((size_t)DT_ * DWP_ * 2);
    __hip_bfloat16* Wcls_t   = (__hip_bfloat16*)alloc((size_t)DT_ * DT_ * 2);
    __hip_bfloat16* Wv_t     = (__hip_bfloat16*)alloc((size_t)DT_ * DF_ * 2);
    __hip_bfloat16* Wbap_t   = (__hip_bfloat16*)alloc((size_t)DT_ * DT_ * 2);
    float*          s_buf    = (float*)         alloc((size_t)B_ * F_ * K_ * 4);
    float2*         pstats   = (float2*)        alloc((size_t)B_ * ASB * K_ * 8);
    float*          pp       = (float*)         alloc((size_t)NSEG * B_ * DT_ * 4);
    __hip_bfloat16* bap_bf   = (__hip_bfloat16*)alloc((size_t)B_ * DT_ * 2);
    float*          yb       = (float*)         alloc((size_t)B_ * DT_ * 4);

    // dynamic batch-chunk: fit ftm_t + v for nb batches in remaining ws
    size_t per_b = (size_t)F_ * DF_ * 2 + (size_t)F_ * DT_ * 2;
    size_t avail = (ws_size > off + 8192) ? ws_size - off - 8192 : 0;
    int nb = (int)(avail / per_b);
    if (nb > B_) nb = B_;
    if (nb < 1) nb = 1;
    __hip_bfloat16* ftm_t = (__hip_bfloat16*)alloc((size_t)nb * F_ * DF_ * 2);
    __hip_bfloat16* v_buf = (__hip_bfloat16*)alloc((size_t)nb * F_ * DT_ * 2);

    hipMemsetAsync(d_out, 0, (size_t)out_size * sizeof(float), stream);

    topk_emb_kernel<<<B_, 256, 0, stream>>>(logits, indices_table, word2vec,
                                            topk_idx, emb_bf);

    if (nb == B_) {
        transpose_all<<<784 + 132 * B_, 256, 0, stream>>>(
            W_emb, Wemb_t, W_cls, Wcls_t, W_v, Wv_t, W_bap, Wbap_t, ftm, ftm_t);
    } else {
        transpose_weights<<<784, 256, 0, stream>>>(
            W_emb, Wemb_t, W_cls, Wcls_t, W_v, Wv_t, W_bap, Wbap_t);
    }

    // cls path (MFMA, n-fastest grid)
    gemm_mfma<1, 1><<<dim3(DT_ / 128, (B_ * K_ + 127) / 128), 256, 0, stream>>>(
        emb_bf, Wemb_t, b_emb, cls1, B_ * K_, DT_, DWP_);
    gemm_mfma<1, 1><<<dim3(DT_ / 128, (B_ * K_ + 127) / 128), 256, 0, stream>>>(
        cls1, Wcls_t, b_cls, cls2, B_ * K_, DT_, DT_);

    // main path, chunked only if ws is small (nb == 64 -> single pass)
    for (int b0 = 0; b0 < B_; b0 += nb) {
        int cb = min(nb, B_ - b0);
        if (nb != B_) {
            transpose_ftm<<<dim3((F_ + 63) / 64, DF_ / 64, cb), 256, 0, stream>>>(
                ftm + (size_t)b0 * DF_ * F_, ftm_t);
        }
        int M = cb * F_;
        gemm_mfma<1, 1><<<dim3(DT_ / 128, (M + 127) / 128), 256, 0, stream>>>(
            ftm_t, Wv_t, b_v, v_buf, M, DT_, DF_);
        float* s_c = s_buf + (size_t)b0 * F_ * K_;
        attn_s_mfma<<<dim3(ASB, cb), 256, 0, stream>>>(
            v_buf, cls2, s_c, pstats, b0);
        o_bap_partial<<<dim3(cb, NSEG), 256, 0, stream>>>(
            v_buf, s_c, pstats, cls2, pp, b0);
    }

    bap_combine<<<B_ * DT_ / 256, 256, 0, stream>>>(pp, bap_bf);
    gemm_mfma<1, 0><<<dim3(DT_ / 128, 1), 256, 0, stream>>>(
        bap_bf, Wbap_t, b_bap, yb, B_, DT_, DT_);
    final_kernel<<<B_, 256, 0, stream>>>(yb, W_fc, b_fc, topk_idx, out);
}